// Round 7
// baseline (444.908 us; speedup 1.0000x reference)
//
#include <hip/hip_runtime.h>
#include <hip/hip_bf16.h>

#define N 8192
#define FIN 512
#define FOUT 64
#define ALPHA 0.2f

typedef __bf16 bf16x8 __attribute__((ext_vector_type(8)));
typedef float f32x4 __attribute__((ext_vector_type(4)));
typedef int i32x4 __attribute__((ext_vector_type(4)));

constexpr int JCH = 256;       // j-chunk staged per barrier
constexpr int CPB = 2;         // chunks per block (block j-span = 512)
constexpr int NCH = 16;        // grid.y partial-sum slices
constexpr int HSTR = JCH + 8;  // 264: LDS stride (odd in 16B units -> swizzled)
constexpr int NW = N / 32;     // 256 bitmask words per row

// ---- workspace layout (bytes) ----
// 0        : Mkey (ordered-uint global max of f_dst; memset 0)
// 4096     : f_src (32 KB)
// 36864    : f_dst (32 KB)
// 69632    : WtG (bf16 [FOUT][FIN], 64 KB)
// 135168   : hT  (bf16 [FOUT][N], 1 MB)
// 1183744  : abit (u32 [N][NW], 8 MB)
// 16777216 : plsum (NCH x N f32, 512 KB)
// 20971520 : pnum  (NCH x N x FOUT f32, 32 MB)

__device__ __forceinline__ unsigned enc_f(float x) {
    unsigned u = __float_as_uint(x);
    return (u & 0x80000000u) ? ~u : (u | 0x80000000u);
}
__device__ __forceinline__ float dec_f(unsigned u) {
    return (u & 0x80000000u) ? __uint_as_float(u & 0x7FFFFFFFu) : __uint_as_float(~u);
}

// ---------- k_wt: WtG[f][k] = bf16(W[k][f]) --------------------------------
__global__ __launch_bounds__(64) void k_wt(const float* __restrict__ W,
                                           __bf16* __restrict__ WtG) {
    const int g = blockIdx.x * 64 + threadIdx.x;  // 0..4095
    const int k = g >> 3;
    const int f0 = (g & 7) * 8;
    const float4 w0 = *(const float4*)(W + (size_t)k * FOUT + f0);
    const float4 w1 = *(const float4*)(W + (size_t)k * FOUT + f0 + 4);
    WtG[(size_t)(f0 + 0) * FIN + k] = (__bf16)w0.x;
    WtG[(size_t)(f0 + 1) * FIN + k] = (__bf16)w0.y;
    WtG[(size_t)(f0 + 2) * FIN + k] = (__bf16)w0.z;
    WtG[(size_t)(f0 + 3) * FIN + k] = (__bf16)w0.w;
    WtG[(size_t)(f0 + 4) * FIN + k] = (__bf16)w1.x;
    WtG[(size_t)(f0 + 5) * FIN + k] = (__bf16)w1.y;
    WtG[(size_t)(f0 + 6) * FIN + k] = (__bf16)w1.z;
    WtG[(size_t)(f0 + 7) * FIN + k] = (__bf16)w1.w;
}

// ---------- k_pack v2: ballot streaming, abit bit j = (adj[i][j] > 0) ------
// Per step: 256B coalesced load, ONE v_cmp (64-bit ballot), one 8B store by
// lane 0. No LDS, no dependent cross-lane chains. 8192 blocks = 32 waves/CU.
__global__ __launch_bounds__(256) void k_pack(const int* __restrict__ adj,
                                              unsigned* __restrict__ abit) {
    const int lane = threadIdx.x & 63;
    const int q = threadIdx.x >> 6;  // quarter of the row
    const int row = blockIdx.x;
    const int* src = adj + (size_t)row * N + q * 2048;
    unsigned long long* dst =
        (unsigned long long*)(abit + (size_t)row * NW + q * 64);
#pragma unroll 4
    for (int s = 0; s < 32; ++s) {
        const int v = __builtin_nontemporal_load(src + s * 64 + lane);
        const unsigned long long b = __ballot(v > 0);
        if (lane == 0) dst[s] = b;
    }
}

// ---------- k12: h=in@W (MFMA) -> f_src/f_dst/Mkey + hT (fused) ------------
__global__ __launch_bounds__(64) void k12(const float* __restrict__ in,
                                          const __bf16* __restrict__ WtG,
                                          const float* __restrict__ a,
                                          float* __restrict__ f_src,
                                          float* __restrict__ f_dst,
                                          unsigned* __restrict__ Mkey,
                                          __bf16* __restrict__ hT) {
    __shared__ __bf16 tb[64][16];
    const int lane = threadIdx.x;
    const int m = lane & 15, quad = lane >> 4;
    const int i0 = blockIdx.x * 16;

    f32x4 acc[4];
#pragma unroll
    for (int t = 0; t < 4; ++t) acc[t] = (f32x4){0.f, 0.f, 0.f, 0.f};

    const float* arow = in + (size_t)(i0 + m) * FIN + quad * 8;
#pragma unroll 2
    for (int k0 = 0; k0 < FIN; k0 += 32) {
        const float4 x0 = *(const float4*)(arow + k0);
        const float4 x1 = *(const float4*)(arow + k0 + 4);
        bf16x8 af;
        af[0] = (__bf16)x0.x; af[1] = (__bf16)x0.y; af[2] = (__bf16)x0.z; af[3] = (__bf16)x0.w;
        af[4] = (__bf16)x1.x; af[5] = (__bf16)x1.y; af[6] = (__bf16)x1.z; af[7] = (__bf16)x1.w;
#pragma unroll
        for (int t = 0; t < 4; ++t) {
            const bf16x8 bf = *(const bf16x8*)(WtG + (size_t)(t * 16 + m) * FIN + k0 + quad * 8);
            acc[t] = __builtin_amdgcn_mfma_f32_16x16x32_bf16(af, bf, acc[t], 0, 0, 0);
        }
    }
    float s1[4], s2[4];
#pragma unroll
    for (int r = 0; r < 4; ++r) { s1[r] = 0.f; s2[r] = 0.f; }
#pragma unroll
    for (int t = 0; t < 4; ++t) {
        const float a1 = a[t * 16 + m], a2 = a[64 + t * 16 + m];
#pragma unroll
        for (int r = 0; r < 4; ++r) {
            s1[r] += acc[t][r] * a1;
            s2[r] += acc[t][r] * a2;
        }
    }
#pragma unroll
    for (int off = 1; off <= 8; off <<= 1)
#pragma unroll
        for (int r = 0; r < 4; ++r) {
            s1[r] += __shfl_xor(s1[r], off);
            s2[r] += __shfl_xor(s2[r], off);
        }
    float lm = -1e30f;
    if (m == 0) {
#pragma unroll
        for (int r = 0; r < 4; ++r) {
            f_src[i0 + quad * 4 + r] = s1[r];
            f_dst[i0 + quad * 4 + r] = s2[r];
            lm = fmaxf(lm, s2[r]);
        }
    }
    lm = fmaxf(lm, __shfl_xor(lm, 16));
    lm = fmaxf(lm, __shfl_xor(lm, 32));
    if (lane == 0) atomicMax(Mkey, enc_f(lm));

#pragma unroll
    for (int t = 0; t < 4; ++t)
#pragma unroll
        for (int r = 0; r < 4; ++r) tb[t * 16 + m][quad * 4 + r] = (__bf16)acc[t][r];
    __syncthreads();
    {
        const int f = lane;
        const bf16x8 v0 = *(const bf16x8*)&tb[f][0];
        const bf16x8 v1 = *(const bf16x8*)&tb[f][8];
        *(bf16x8*)(hT + (size_t)f * N + i0) = v0;
        *(bf16x8*)(hT + (size_t)f * N + i0 + 8) = v1;
    }
}

// ---------- k3: bitmask -> softmax weights (in A-frag layout) -> PV --------
__global__ __launch_bounds__(256) void k3_attn(const unsigned* __restrict__ abit,
                                               const float* __restrict__ f_src,
                                               const float* __restrict__ fdstG,
                                               const unsigned* __restrict__ Mkey,
                                               const __bf16* __restrict__ hT,
                                               float* __restrict__ pnum,
                                               float* __restrict__ plsum) {
    __shared__ __bf16 sh[64 * HSTR];  // hT tile, 33,792 B
    __shared__ float sfd[JCH * CPB];  // 2 KB
    const int tid = threadIdx.x;
    const int wv = tid >> 6, lane = tid & 63;
    const int m = lane & 15, quad = lane >> 4;
    const int i0w = blockIdx.x * 256 + wv * 64;  // wave's 64 rows
    const int jb = blockIdx.y * (JCH * CPB);
    const float LOG2E = 1.44269504088896f;

    if (tid < (JCH * CPB) / 4) *(f32x4*)&sfd[tid * 4] = *(const f32x4*)(fdstG + jb + tid * 4);

    const float M = dec_f(*Mkey);
    float fs[4], sht[4];
#pragma unroll
    for (int mt = 0; mt < 4; ++mt) {
        fs[mt] = f_src[i0w + mt * 16 + m];
        const float tt = fs[mt] + M;
        sht[mt] = fmaxf(tt, ALPHA * tt);  // leaky(fs + max f_dst) >= every e
    }

    f32x4 acc[4][4], accl[4];
#pragma unroll
    for (int mt = 0; mt < 4; ++mt) {
        accl[mt] = (f32x4){0.f, 0.f, 0.f, 0.f};
#pragma unroll
        for (int t = 0; t < 4; ++t) acc[mt][t] = (f32x4){0.f, 0.f, 0.f, 0.f};
    }

    bf16x8 bones;  // ones-column B -> row sums (denominator)
#pragma unroll
    for (int jj = 0; jj < 8; ++jj) bones[jj] = (__bf16)(m == 0 ? 1.0f : 0.0f);

    for (int c = 0; c < CPB; ++c) {
        const int jc = jb + c * JCH;
        __syncthreads();  // protect sh reuse
#pragma unroll
        for (int k = 0; k < 8; ++k) {
            const int s = tid + k * 256;  // 2048 bf16x8 slots
            const int f = s >> 5, off = (s & 31) * 8;
            *(bf16x8*)&sh[f * HSTR + off] = *(const bf16x8*)(hT + (size_t)f * N + jc + off);
        }
        __syncthreads();

#pragma unroll
        for (int s = 0; s < 8; ++s) {
            const int widx = (jc >> 5) + s;
            const f32x4 fd0 = *(const f32x4*)&sfd[c * JCH + s * 32 + quad * 8];
            const f32x4 fd1 = *(const f32x4*)&sfd[c * JCH + s * 32 + quad * 8 + 4];
            bf16x8 B[4];
#pragma unroll
            for (int t = 0; t < 4; ++t)
                B[t] = *(const bf16x8*)&sh[(t * 16 + m) * HSTR + s * 32 + quad * 8];
#pragma unroll
            for (int mt = 0; mt < 4; ++mt) {
                const unsigned mw = abit[(size_t)(i0w + mt * 16 + m) * NW + widx];
                const unsigned bits = mw >> (quad * 8);
                bf16x8 af;
#pragma unroll
                for (int jj = 0; jj < 8; ++jj) {
                    float e = fs[mt] + (jj < 4 ? fd0[jj] : fd1[jj - 4]);
                    e = fmaxf(e, ALPHA * e);
                    const float ex = __builtin_amdgcn_exp2f((e - sht[mt]) * LOG2E);
                    af[jj] = (__bf16)(((bits >> jj) & 1u) ? ex : 0.f);
                }
#pragma unroll
                for (int t = 0; t < 4; ++t)
                    acc[mt][t] = __builtin_amdgcn_mfma_f32_16x16x32_bf16(af, B[t], acc[mt][t], 0, 0, 0);
                accl[mt] = __builtin_amdgcn_mfma_f32_16x16x32_bf16(af, bones, accl[mt], 0, 0, 0);
            }
        }
    }

    float* pn = pnum + (size_t)blockIdx.y * N * FOUT;
#pragma unroll
    for (int mt = 0; mt < 4; ++mt) {
#pragma unroll
        for (int t = 0; t < 4; ++t)
#pragma unroll
            for (int r = 0; r < 4; ++r)
                pn[(size_t)(i0w + mt * 16 + quad * 4 + r) * FOUT + t * 16 + m] = acc[mt][t][r];
        if (m == 0) {
#pragma unroll
            for (int r = 0; r < 4; ++r)
                plsum[(size_t)blockIdx.y * N + i0w + mt * 16 + quad * 4 + r] = accl[mt][r];
        }
    }
}

// ---------- k4: reduce partials, out = leaky(num/lsum, 0.01) ---------------
__global__ __launch_bounds__(256) void k4_norm(const float* __restrict__ pnum,
                                               const float* __restrict__ plsum,
                                               float* __restrict__ out) {
    const int idx = blockIdx.x * 256 + threadIdx.x;  // over N*FOUT
    const int row = idx >> 6;
    float s = 0.f, l = 0.f;
#pragma unroll
    for (int c = 0; c < NCH; ++c) {
        s += pnum[(size_t)c * N * FOUT + idx];
        l += plsum[(size_t)c * N + row];
    }
    const float v = s / (l > 0.f ? l : 1.f);
    out[idx] = v > 0.f ? v : 0.01f * v;
}

extern "C" void kernel_launch(void* const* d_in, const int* in_sizes, int n_in,
                              void* d_out, int out_size, void* d_ws, size_t ws_size,
                              hipStream_t stream) {
    const float* in = (const float*)d_in[0];
    const int* adj = (const int*)d_in[1];
    const float* W = (const float*)d_in[2];
    const float* a = (const float*)d_in[3];
    float* out = (float*)d_out;

    char* ws = (char*)d_ws;
    unsigned* Mkey = (unsigned*)ws;
    float* f_src = (float*)(ws + 4096);
    float* f_dst = (float*)(ws + 36864);
    __bf16* WtG = (__bf16*)(ws + 69632);
    __bf16* hT = (__bf16*)(ws + 135168);
    unsigned* abit = (unsigned*)(ws + 1183744);
    float* plsum = (float*)(ws + 16777216);
    float* pnum = (float*)(ws + 20971520);

    hipMemsetAsync(ws, 0, 64, stream);  // Mkey only

    // non-adj kernels first: give the harness's adj-restore writebacks time
    // to drain before we stream adj.
    k_wt<<<64, 64, 0, stream>>>(W, WtG);
    k12<<<N / 16, 64, 0, stream>>>(in, WtG, a, f_src, f_dst, Mkey, hT);
    k_pack<<<N, 256, 0, stream>>>(adj, abit);

    dim3 g3(N / 256, NCH);
    k3_attn<<<g3, 256, 0, stream>>>(abit, f_src, f_dst, Mkey, hT, pnum, plsum);
    k4_norm<<<(N * FOUT) / 256, 256, 0, stream>>>(pnum, plsum, out);
}